// Round 2
// baseline (724.418 us; speedup 1.0000x reference)
//
#include <hip/hip_runtime.h>

#define NCOL 110592          // 48*48*48
#define CN   (NCOL * 64)     // elements per batch
#define PAD  66              // Kt row stride in floats (even -> 8B-aligned b64 reads)

typedef __attribute__((ext_vector_type(8))) __bf16 bf16x8;
typedef __attribute__((ext_vector_type(4))) float  f32x4;
typedef __attribute__((ext_vector_type(2))) float  f32x2;

// ---------------------------------------------------------------------------
// K1: partial Gram G_partial = K_chunk * K_chunk^T via bf16 MFMA.
// Fragments load directly from global (Gram: A-frag and B-frag layouts match).
// ---------------------------------------------------------------------------
__global__ __launch_bounds__(256) void k_gram(const float* __restrict__ x,
                                              float* __restrict__ part,
                                              int steps) {
    const int b     = blockIdx.y;
    const int chunk = blockIdx.x;
    const int tid   = threadIdx.x;
    const int w     = tid >> 6;
    const int lane  = tid & 63;
    const int r     = lane & 15;
    const int q     = lane >> 4;

    const float* xb = x + (size_t)b * CN;

    f32x4 acc0 = {0.f, 0.f, 0.f, 0.f};
    f32x4 acc1 = {0.f, 0.f, 0.f, 0.f};
    f32x4 acc2 = {0.f, 0.f, 0.f, 0.f};
    f32x4 acc3 = {0.f, 0.f, 0.f, 0.f};

    const int kbase = chunk * steps * 32 + q * 8;

    for (int s = 0; s < steps; ++s) {
        const int k0 = kbase + s * 32;
        bf16x8 frag[4];
#pragma unroll
        for (int i = 0; i < 4; ++i) {
            const float* p = xb + (size_t)(i * 16 + r) * NCOL + k0;
            f32x4 lo = *(const f32x4*)p;
            f32x4 hi = *(const f32x4*)(p + 4);
            bf16x8 f;
            f[0] = (__bf16)lo[0]; f[1] = (__bf16)lo[1];
            f[2] = (__bf16)lo[2]; f[3] = (__bf16)lo[3];
            f[4] = (__bf16)hi[0]; f[5] = (__bf16)hi[1];
            f[6] = (__bf16)hi[2]; f[7] = (__bf16)hi[3];
            frag[i] = f;
        }
        bf16x8 af = (w == 0) ? frag[0] : (w == 1) ? frag[1]
                  : (w == 2) ? frag[2] : frag[3];
        acc0 = __builtin_amdgcn_mfma_f32_16x16x32_bf16(af, frag[0], acc0, 0, 0, 0);
        acc1 = __builtin_amdgcn_mfma_f32_16x16x32_bf16(af, frag[1], acc1, 0, 0, 0);
        acc2 = __builtin_amdgcn_mfma_f32_16x16x32_bf16(af, frag[2], acc2, 0, 0, 0);
        acc3 = __builtin_amdgcn_mfma_f32_16x16x32_bf16(af, frag[3], acc3, 0, 0, 0);
    }

    float* pp = part + (size_t)(b * gridDim.x + chunk) * 4096;
#pragma unroll
    for (int rr = 0; rr < 4; ++rr) {
        const int m = w * 16 + q * 4 + rr;
        pp[m * 64 + (0 * 16 + r)] = acc0[rr];
        pp[m * 64 + (1 * 16 + r)] = acc1[rr];
        pp[m * 64 + (2 * 16 + r)] = acc2[rr];
        pp[m * 64 + (3 * 16 + r)] = acc3[rr];
    }
}

// ---------------------------------------------------------------------------
// K2: fused reduce + affinity.  A = sigmoid((ΣG_partial)^2)  [no gamma, no I]
// ---------------------------------------------------------------------------
__global__ __launch_bounds__(256) void k_post(const float* __restrict__ part,
                                              float* __restrict__ A,
                                              int chunks) {
    const int b = blockIdx.x;
    __shared__ float Gs[64 * 65];
    for (int id = threadIdx.x; id < 4096; id += 256) {
        float s = 0.f;
        for (int p = 0; p < chunks; ++p)
            s += part[(size_t)(b * chunks + p) * 4096 + id];
        Gs[(id >> 6) * 65 + (id & 63)] = s;
    }
    __syncthreads();
    for (int id = threadIdx.x; id < 4096; id += 256) {
        const int c = id >> 6, e = id & 63;
        float dot = 0.f;
#pragma unroll
        for (int d = 0; d < 64; ++d)
            dot += Gs[c * 65 + d] * Gs[e * 65 + d];
        A[b * 4096 + id] = 1.0f / (1.0f + __expf(-dot));
    }
}

// ---------------------------------------------------------------------------
// K3: out = gamma * (A @ K) + x  via bf16 MFMA; +x term exact fp32 from LDS.
// Block = 256 thr = 4 waves, strip of 512 cols, 8 tiles of 64 cols.
// LDS: Kt[n_local][d] fp32, stride PAD=66.
// A-fragments preloaded to registers once per block (A is 16KB/batch, L2-hot).
// ---------------------------------------------------------------------------
__global__ __launch_bounds__(256) void k_apply(const float* __restrict__ x,
                                               const float* __restrict__ A,
                                               const float* __restrict__ gptr,
                                               float* __restrict__ out) {
    const int b    = blockIdx.y;
    const int tid  = threadIdx.x;
    const int w    = tid >> 6;
    const int lane = tid & 63;
    const int r    = lane & 15;
    const int q    = lane >> 4;
    const float gamma = gptr[0];

    const float* xb = x + (size_t)b * CN;
    float*       ob = out + (size_t)b * CN;
    const float* Ab = A + b * 4096;

    __shared__ float Kt[64 * PAD];

    // A-fragments: afr[mt][ks] holds A[mt*16+r][ks*32+q*8 .. +7]
    bf16x8 afr[4][2];
#pragma unroll
    for (int mt = 0; mt < 4; ++mt)
#pragma unroll
        for (int ks = 0; ks < 2; ++ks) {
            const float* p = Ab + (mt * 16 + r) * 64 + ks * 32 + q * 8;
            f32x4 lo = *(const f32x4*)p;
            f32x4 hi = *(const f32x4*)(p + 4);
            bf16x8 f;
            f[0] = (__bf16)lo[0]; f[1] = (__bf16)lo[1];
            f[2] = (__bf16)lo[2]; f[3] = (__bf16)lo[3];
            f[4] = (__bf16)hi[0]; f[5] = (__bf16)hi[1];
            f[6] = (__bf16)hi[2]; f[7] = (__bf16)hi[3];
            afr[mt][ks] = f;
        }

    const int nl = w * 16 + r;   // local column owned in compute/epilogue

    for (int it = 0; it < 8; ++it) {
        const int n0 = blockIdx.x * 512 + it * 64;
        __syncthreads();                       // previous tile fully consumed
        // stage 64x64 fp32 tile transposed: Kt[n][d] = x[d][n0+n]
#pragma unroll
        for (int i = 0; i < 4; ++i) {
            const int v    = tid + 256 * i;
            const int row  = v >> 4;           // d
            const int quad = v & 15;           // n quad
            f32x4 vec = *(const f32x4*)(xb + (size_t)row * NCOL + n0 + quad * 4);
#pragma unroll
            for (int j = 0; j < 4; ++j)
                Kt[(quad * 4 + j) * PAD + row] = vec[j];
        }
        __syncthreads();

        f32x4 acc[4] = {{0.f,0.f,0.f,0.f},{0.f,0.f,0.f,0.f},
                        {0.f,0.f,0.f,0.f},{0.f,0.f,0.f,0.f}};
#pragma unroll
        for (int ks = 0; ks < 2; ++ks) {
            const float* kp = &Kt[nl * PAD + ks * 32 + q * 8];
            f32x2 p0 = *(const f32x2*)(kp + 0);
            f32x2 p1 = *(const f32x2*)(kp + 2);
            f32x2 p2 = *(const f32x2*)(kp + 4);
            f32x2 p3 = *(const f32x2*)(kp + 6);
            bf16x8 bf;
            bf[0] = (__bf16)p0[0]; bf[1] = (__bf16)p0[1];
            bf[2] = (__bf16)p1[0]; bf[3] = (__bf16)p1[1];
            bf[4] = (__bf16)p2[0]; bf[5] = (__bf16)p2[1];
            bf[6] = (__bf16)p3[0]; bf[7] = (__bf16)p3[1];
#pragma unroll
            for (int mt = 0; mt < 4; ++mt)
                acc[mt] = __builtin_amdgcn_mfma_f32_16x16x32_bf16(afr[mt][ks], bf, acc[mt], 0, 0, 0);
        }

        // epilogue: out[c][n] = gamma*acc + x[c][n] (exact fp32 from LDS)
        const int n = n0 + nl;
#pragma unroll
        for (int mt = 0; mt < 4; ++mt)
#pragma unroll
            for (int rr = 0; rr < 4; ++rr) {
                const int c = mt * 16 + q * 4 + rr;
                ob[(size_t)c * NCOL + n] = gamma * acc[mt][rr] + Kt[nl * PAD + c];
            }
    }
}

// ---------------------------------------------------------------------------
extern "C" void kernel_launch(void* const* d_in, const int* in_sizes, int n_in,
                              void* d_out, int out_size, void* d_ws, size_t ws_size,
                              hipStream_t stream) {
    const float* x    = (const float*)d_in[0];
    const float* gptr = (const float*)d_in[1];
    float*       out  = (float*)d_out;
    float*       ws   = (float*)d_ws;

    int chunks = 64;
    auto need = [](int ch) { return (size_t)(8 * ch + 8) * 4096 * 4; };
    if (ws_size < need(64)) chunks = 32;
    if (ws_size < need(32)) chunks = 8;
    if (ws_size < need(8))  chunks = 2;
    const int steps = 3456 / chunks;   // 3456 k32-steps per batch

    float* part = ws;
    float* Aff  = ws + (size_t)8 * chunks * 4096;

    k_gram <<<dim3(chunks, 8), 256, 0, stream>>>(x, part, steps);
    k_post <<<8,               256, 0, stream>>>(part, Aff, chunks);
    k_apply<<<dim3(216, 8),    256, 0, stream>>>(x, Aff, gptr, out);
}